// Round 1
// baseline (236.847 us; speedup 1.0000x reference)
//
#include <hip/hip_runtime.h>
#include <math.h>

#define SEQ 5
#define EMBC 64   // EMB == CLUSTER == 64

__device__ __forceinline__ float wave_max(float v) {
    #pragma unroll
    for (int o = 32; o > 0; o >>= 1) v = fmaxf(v, __shfl_xor(v, o, 64));
    return v;
}
__device__ __forceinline__ float wave_sum(float v) {
    #pragma unroll
    for (int o = 32; o > 0; o >>= 1) v += __shfl_xor(v, o, 64);
    return v;
}

__global__ __launch_bounds__(256) void rumc_kernel(
    const int* __restrict__ u_idx, const int* __restrict__ X_idx,
    const int* __restrict__ y_idx,
    const float* __restrict__ item_emb, const float* __restrict__ user_emb,
    const float* __restrict__ ae_raw, const float* __restrict__ w_raw,
    float* __restrict__ out, int B)
{
    // s_wT[d*64 + c] = softmax_over_c(w_raw*500)[c][d]  (transposed for the v-loop)
    __shared__ float s_wT[EMBC * EMBC];
    __shared__ float s_inv[EMBC];

    const int t = threadIdx.x;

    // ---- column softmax of w_raw*500 (axis=0), written transposed ----
    if (t < EMBC) {
        const int d = t;
        float m = -3.4e38f;
        for (int c = 0; c < EMBC; ++c)
            m = fmaxf(m, w_raw[c * EMBC + d]);
        m *= 500.0f;                      // scale > 0 -> max commutes
        float sum = 0.0f;
        for (int c = 0; c < EMBC; ++c) {
            float e = __expf(w_raw[c * EMBC + d] * 500.0f - m);
            s_wT[d * EMBC + c] = e;
            sum += e;
        }
        s_inv[d] = 1.0f / sum;
    }
    __syncthreads();
    for (int i = t; i < EMBC * EMBC; i += 256)
        s_wT[i] *= s_inv[i >> 6];
    __syncthreads();

    const int wave = t >> 6;
    const int lane = t & 63;
    const int b = blockIdx.x * 4 + wave;
    if (b < B) {
        const int yi = y_idx[b];
        const int ui = u_idx[b];

        // ---- ae[y] row softmax (lane = cluster) ----
        float aey = ae_raw[yi * EMBC + lane] * 50.0f;
        aey = __expf(aey - wave_max(aey));
        aey /= wave_sum(aey);

        // ---- v[c] = sum_d w[c][d] * aey[d]   (lane = c) ----
        float v = 0.0f;
        #pragma unroll
        for (int d = 0; d < EMBC; ++d)
            v = fmaf(s_wT[d * EMBC + lane], __shfl(aey, d, 64), v);

        const float ye = (yi == 0) ? 0.0f : item_emb[yi * EMBC + lane];
        const float ue = user_emb[ui * EMBC + lane];

        float xe[SEQ];
        float sc[SEQ];
        #pragma unroll
        for (int s = 0; s < SEQ; ++s) {
            const int xi = X_idx[b * SEQ + s];

            // ae[x_s] row softmax
            float ax = ae_raw[xi * EMBC + lane] * 50.0f;
            ax = __expf(ax - wave_max(ax));
            ax /= wave_sum(ax);

            const float x_e = (xi == 0) ? 0.0f : item_emb[xi * EMBC + lane];
            xe[s] = x_e;

            const float fac = wave_sum(ax * v);       // aeX . (w @ aeY)
            const float dot = wave_sum(x_e * ye);     // X_emb . y_emb
            const float tf = 1.0f - (float)(SEQ - 1 - s) * 0.1f;
            sc[s] = dot * __expf(fac) * tf;           // BETA == 1
        }

        // ---- softmax over SEQ (scores identical on all lanes) ----
        float ms = sc[0];
        #pragma unroll
        for (int s = 1; s < SEQ; ++s) ms = fmaxf(ms, sc[s]);
        float Z = 0.0f;
        #pragma unroll
        for (int s = 0; s < SEQ; ++s) { sc[s] = __expf(sc[s] - ms); Z += sc[s]; }
        const float invZ = 1.0f / Z;

        // ---- p = sum_s z_s * X_emb[s];  out = sigmoid((p*alpha + u_emb) . y_emb) ----
        float p = 0.0f;
        #pragma unroll
        for (int s = 0; s < SEQ; ++s) p = fmaf(xe[s], sc[s] * invZ, p);
        const float pu = fmaf(p, 0.2f, ue);
        const float fin = wave_sum(pu * ye);
        if (lane == 0)
            out[b] = 1.0f / (1.0f + __expf(-fin));
    }
}

extern "C" void kernel_launch(void* const* d_in, const int* in_sizes, int n_in,
                              void* d_out, int out_size, void* d_ws, size_t ws_size,
                              hipStream_t stream) {
    const int*   u        = (const int*)d_in[0];
    const int*   X        = (const int*)d_in[1];
    const int*   y        = (const int*)d_in[2];
    const float* item_emb = (const float*)d_in[3];
    const float* user_emb = (const float*)d_in[4];
    const float* ae_raw   = (const float*)d_in[5];
    const float* w_raw    = (const float*)d_in[6];
    float*       out      = (float*)d_out;

    const int B = in_sizes[0];
    const int grid = (B + 3) / 4;
    rumc_kernel<<<grid, 256, 0, stream>>>(u, X, y, item_emb, user_emb,
                                          ae_raw, w_raw, out, B);
}

// Round 2
// 165.557 us; speedup vs baseline: 1.4306x; 1.4306x over previous
//
#include <hip/hip_runtime.h>
#include <math.h>

#define SEQ 5
#define EMBC 64   // EMB == CLUSTER == 64

__device__ __forceinline__ float wave_max(float v) {
    #pragma unroll
    for (int o = 32; o > 0; o >>= 1) v = fmaxf(v, __shfl_xor(v, o, 64));
    return v;
}
__device__ __forceinline__ float wave_sum(float v) {
    #pragma unroll
    for (int o = 32; o > 0; o >>= 1) v += __shfl_xor(v, o, 64);
    return v;
}

// ---- Kernel A: column-softmax of w_raw*500 (axis=0), stored TRANSPOSED ----
// block d (64 blocks), lane c: wT[d*64+c] = softmax_c(w_raw[:,d]*500)[c]
__global__ __launch_bounds__(64) void wprep_kernel(
    const float* __restrict__ w_raw, float* __restrict__ wT)
{
    const int d = blockIdx.x;
    const int c = threadIdx.x;
    float x = w_raw[c * EMBC + d] * 500.0f;
    const float m = wave_max(x);
    const float e = __expf(x - m);
    const float s = wave_sum(e);
    wT[d * EMBC + c] = e / s;   // coalesced write
}

// ---- Kernel B: one wave per batch element, no LDS, no barriers ----
__global__ __launch_bounds__(256) void rumc_kernel(
    const int* __restrict__ u_idx, const int* __restrict__ X_idx,
    const int* __restrict__ y_idx,
    const float* __restrict__ item_emb, const float* __restrict__ user_emb,
    const float* __restrict__ ae_raw, const float* __restrict__ wT,
    float* __restrict__ out, int B)
{
    const int t = threadIdx.x;
    const int wave = t >> 6;
    const int lane = t & 63;
    const int b = blockIdx.x * 4 + wave;
    if (b >= B) return;

    // ---- indices ----
    const int yi = y_idx[b];
    const int ui = u_idx[b];
    int xi[SEQ];
    #pragma unroll
    for (int s = 0; s < SEQ; ++s) xi[s] = X_idx[b * SEQ + s];

    // ---- issue ALL gathers up front (independent loads) ----
    const float aey_r = ae_raw[yi * EMBC + lane];
    float ax_r[SEQ];
    #pragma unroll
    for (int s = 0; s < SEQ; ++s) ax_r[s] = ae_raw[xi[s] * EMBC + lane];
    const float ye_r = item_emb[yi * EMBC + lane];
    float xe[SEQ];
    #pragma unroll
    for (int s = 0; s < SEQ; ++s) xe[s] = item_emb[xi[s] * EMBC + lane];
    const float ue = user_emb[ui * EMBC + lane];

    // padding_idx = 0 -> zero embedding row (ae row 0 is NOT zeroed)
    const float ye = (yi == 0) ? 0.0f : ye_r;
    #pragma unroll
    for (int s = 0; s < SEQ; ++s) if (xi[s] == 0) xe[s] = 0.0f;

    // ---- ae[y] row softmax (lane = cluster) ----
    float aey = aey_r * 50.0f;
    aey = __expf(aey - wave_max(aey));
    aey /= wave_sum(aey);

    // ---- v[c] = sum_d w[c][d]*aey[d]  (lane = c); wT is L1-resident 16 KB ----
    float v = 0.0f;
    #pragma unroll
    for (int d = 0; d < EMBC; ++d)
        v = fmaf(wT[d * EMBC + lane], __shfl(aey, d, 64), v);

    // ---- per-position scores ----
    float sc[SEQ];
    #pragma unroll
    for (int s = 0; s < SEQ; ++s) {
        float ax = ax_r[s] * 50.0f;
        ax = __expf(ax - wave_max(ax));
        ax /= wave_sum(ax);
        const float fac = wave_sum(ax * v);       // aeX . (w @ aeY)
        const float dot = wave_sum(xe[s] * ye);   // X_emb . y_emb
        const float tf = 1.0f - (float)(SEQ - 1 - s) * 0.1f;
        sc[s] = dot * __expf(fac) * tf;           // BETA == 1
    }

    // ---- softmax over SEQ (identical on all lanes) ----
    float ms = sc[0];
    #pragma unroll
    for (int s = 1; s < SEQ; ++s) ms = fmaxf(ms, sc[s]);
    float Z = 0.0f;
    #pragma unroll
    for (int s = 0; s < SEQ; ++s) { sc[s] = __expf(sc[s] - ms); Z += sc[s]; }
    const float invZ = 1.0f / Z;

    // ---- p = sum_s z_s * X_emb[s];  out = sigmoid((p*0.2 + u_emb) . y_emb) ----
    float p = 0.0f;
    #pragma unroll
    for (int s = 0; s < SEQ; ++s) p = fmaf(xe[s], sc[s] * invZ, p);
    const float pu = fmaf(p, 0.2f, ue);
    const float fin = wave_sum(pu * ye);
    if (lane == 0)
        out[b] = 1.0f / (1.0f + __expf(-fin));
}

extern "C" void kernel_launch(void* const* d_in, const int* in_sizes, int n_in,
                              void* d_out, int out_size, void* d_ws, size_t ws_size,
                              hipStream_t stream) {
    const int*   u        = (const int*)d_in[0];
    const int*   X        = (const int*)d_in[1];
    const int*   y        = (const int*)d_in[2];
    const float* item_emb = (const float*)d_in[3];
    const float* user_emb = (const float*)d_in[4];
    const float* ae_raw   = (const float*)d_in[5];
    const float* w_raw    = (const float*)d_in[6];
    float*       out      = (float*)d_out;
    float*       wT       = (float*)d_ws;   // 64*64 floats = 16 KB

    const int B = in_sizes[0];

    wprep_kernel<<<EMBC, EMBC, 0, stream>>>(w_raw, wT);
    rumc_kernel<<<(B + 3) / 4, 256, 0, stream>>>(u, X, y, item_emb, user_emb,
                                                 ae_raw, wT, out, B);
}

// Round 3
// 147.424 us; speedup vs baseline: 1.6066x; 1.1230x over previous
//
#include <hip/hip_runtime.h>
#include <math.h>

#define SEQ 5
#define EMBC 64   // EMB == CLUSTER == 64

typedef float4 f4;

// reductions within a 16-lane subgroup (wave64 = 4 subgroups of 16)
__device__ __forceinline__ float sub_sum(float v) {
    #pragma unroll
    for (int o = 8; o > 0; o >>= 1) v += __shfl_xor(v, o, 64);
    return v;
}
__device__ __forceinline__ float sub_max(float v) {
    #pragma unroll
    for (int o = 8; o > 0; o >>= 1) v = fmaxf(v, __shfl_xor(v, o, 64));
    return v;
}
__device__ __forceinline__ float wave_max64(float v) {
    #pragma unroll
    for (int o = 32; o > 0; o >>= 1) v = fmaxf(v, __shfl_xor(v, o, 64));
    return v;
}
__device__ __forceinline__ float wave_sum64(float v) {
    #pragma unroll
    for (int o = 32; o > 0; o >>= 1) v += __shfl_xor(v, o, 64);
    return v;
}
__device__ __forceinline__ float dot4(f4 a, f4 b) {
    return fmaf(a.x, b.x, fmaf(a.y, b.y, fmaf(a.z, b.z, a.w * b.w)));
}
__device__ __forceinline__ f4 fma4(f4 a, float s, f4 c) {
    f4 r; r.x = fmaf(a.x, s, c.x); r.y = fmaf(a.y, s, c.y);
          r.z = fmaf(a.z, s, c.z); r.w = fmaf(a.w, s, c.w); return r;
}
// row softmax of a 64-float vector distributed as float4 over a 16-lane subgroup
__device__ __forceinline__ f4 sub_softmax(f4 a, float scale) {
    a.x *= scale; a.y *= scale; a.z *= scale; a.w *= scale;
    const float m = sub_max(fmaxf(fmaxf(a.x, a.y), fmaxf(a.z, a.w)));
    f4 e; e.x = __expf(a.x - m); e.y = __expf(a.y - m);
          e.z = __expf(a.z - m); e.w = __expf(a.w - m);
    const float inv = 1.0f / sub_sum(((e.x + e.y) + (e.z + e.w)));
    e.x *= inv; e.y *= inv; e.z *= inv; e.w *= inv;
    return e;
}

// ---- Kernel A: column-softmax of w_raw*500 (axis=0), stored TRANSPOSED ----
// block d (64 blocks), lane c: wT[d*64+c] = softmax_c(w_raw[:,d]*500)[c]
__global__ __launch_bounds__(64) void wprep_kernel(
    const float* __restrict__ w_raw, float* __restrict__ wT)
{
    const int d = blockIdx.x;
    const int c = threadIdx.x;
    float x = w_raw[c * EMBC + d] * 500.0f;
    const float m = wave_max64(x);
    const float e = __expf(x - m);
    const float s = wave_sum64(e);
    wT[d * EMBC + c] = e / s;   // coalesced write
}

// ---- Kernel B: 16-lane subgroup per batch element; float4 row gathers ----
__global__ __launch_bounds__(256) void rumc_kernel(
    const int* __restrict__ u_idx, const int* __restrict__ X_idx,
    const int* __restrict__ y_idx,
    const float* __restrict__ item_emb, const float* __restrict__ user_emb,
    const float* __restrict__ ae_raw, const float* __restrict__ wT,
    float* __restrict__ out, int B)
{
    const int t    = threadIdx.x;
    const int wave = t >> 6;
    const int lane = t & 63;
    const int sub  = lane >> 4;    // subgroup 0..3
    const int sl   = lane & 15;    // lane within subgroup

    int b = (blockIdx.x * 4 + wave) * 4 + sub;
    const bool live = (b < B);
    if (!live) b = B - 1;

    // ---- indices (4 distinct rows per wave -> few transactions) ----
    const int yi = y_idx[b];
    const int ui = u_idx[b];
    int xi[SEQ];
    #pragma unroll
    for (int s = 0; s < SEQ; ++s) xi[s] = X_idx[b * SEQ + s];

    const f4* __restrict__ item4 = (const f4*)item_emb;
    const f4* __restrict__ user4 = (const f4*)user_emb;
    const f4* __restrict__ ae4   = (const f4*)ae_raw;
    const f4* __restrict__ wT4   = (const f4*)wT;

    // ---- all row gathers up front: 12 float4 loads, each 1 KB/wave ----
    f4 aey = ae4[yi * 16 + sl];
    f4 ax[SEQ];
    #pragma unroll
    for (int s = 0; s < SEQ; ++s) ax[s] = ae4[xi[s] * 16 + sl];
    f4 ye = item4[yi * 16 + sl];
    f4 xe[SEQ];
    #pragma unroll
    for (int s = 0; s < SEQ; ++s) xe[s] = item4[xi[s] * 16 + sl];
    f4 ue = user4[ui * 16 + sl];

    // padding_idx = 0 -> zero embedding row (ae row 0 is NOT zeroed)
    if (yi == 0) { ye.x = ye.y = ye.z = ye.w = 0.0f; }
    #pragma unroll
    for (int s = 0; s < SEQ; ++s)
        if (xi[s] == 0) { xe[s].x = xe[s].y = xe[s].z = xe[s].w = 0.0f; }

    // ---- ae[y] row softmax ----
    aey = sub_softmax(aey, 50.0f);

    // ---- v[c] = sum_d w[c][d]*aey[d]; lane holds c = sl*4..sl*4+3 ----
    f4 v; v.x = v.y = v.z = v.w = 0.0f;
    const int base = lane & 48;    // first lane of this subgroup
    #pragma unroll
    for (int dd = 0; dd < 16; ++dd) {
        f4 ad;
        ad.x = __shfl(aey.x, base + dd, 64);
        ad.y = __shfl(aey.y, base + dd, 64);
        ad.z = __shfl(aey.z, base + dd, 64);
        ad.w = __shfl(aey.w, base + dd, 64);
        const f4 w0 = wT4[(dd * 4 + 0) * 16 + sl];
        const f4 w1 = wT4[(dd * 4 + 1) * 16 + sl];
        const f4 w2 = wT4[(dd * 4 + 2) * 16 + sl];
        const f4 w3 = wT4[(dd * 4 + 3) * 16 + sl];
        v = fma4(w0, ad.x, v);
        v = fma4(w1, ad.y, v);
        v = fma4(w2, ad.z, v);
        v = fma4(w3, ad.w, v);
    }

    // ---- per-position scores ----
    float sc[SEQ];
    #pragma unroll
    for (int s = 0; s < SEQ; ++s) {
        const f4 a = sub_softmax(ax[s], 50.0f);
        const float fac = sub_sum(dot4(a, v));      // aeX . (w @ aeY)
        const float dot = sub_sum(dot4(xe[s], ye)); // X_emb . y_emb
        const float tf = 1.0f - (float)(SEQ - 1 - s) * 0.1f;
        sc[s] = dot * __expf(fac) * tf;             // BETA == 1
    }

    // ---- softmax over SEQ (identical within subgroup) ----
    float ms = sc[0];
    #pragma unroll
    for (int s = 1; s < SEQ; ++s) ms = fmaxf(ms, sc[s]);
    float Z = 0.0f;
    #pragma unroll
    for (int s = 0; s < SEQ; ++s) { sc[s] = __expf(sc[s] - ms); Z += sc[s]; }
    const float invZ = 1.0f / Z;

    // ---- p = sum_s z_s*X_emb[s]; out = sigmoid((p*0.2 + u_emb) . y_emb) ----
    f4 p; p.x = p.y = p.z = p.w = 0.0f;
    #pragma unroll
    for (int s = 0; s < SEQ; ++s) p = fma4(xe[s], sc[s] * invZ, p);
    const f4 pu = fma4(p, 0.2f, ue);
    const float fin = sub_sum(dot4(pu, ye));
    if (live && sl == 0)
        out[b] = 1.0f / (1.0f + __expf(-fin));
}

extern "C" void kernel_launch(void* const* d_in, const int* in_sizes, int n_in,
                              void* d_out, int out_size, void* d_ws, size_t ws_size,
                              hipStream_t stream) {
    const int*   u        = (const int*)d_in[0];
    const int*   X        = (const int*)d_in[1];
    const int*   y        = (const int*)d_in[2];
    const float* item_emb = (const float*)d_in[3];
    const float* user_emb = (const float*)d_in[4];
    const float* ae_raw   = (const float*)d_in[5];
    const float* w_raw    = (const float*)d_in[6];
    float*       out      = (float*)d_out;
    float*       wT       = (float*)d_ws;   // 64*64 floats = 16 KB

    const int B = in_sizes[0];

    wprep_kernel<<<EMBC, EMBC, 0, stream>>>(w_raw, wT);
    rumc_kernel<<<(B + 15) / 16, 256, 0, stream>>>(u, X, y, item_emb, user_emb,
                                                   ae_raw, wT, out, B);
}